// Round 13
// baseline (197.706 us; speedup 1.0000x reference)
//
#include <hip/hip_runtime.h>

#define NPTS 8192
#define KSEL 33    // rank 0 (self) + 32 neighbors
#define SCAP 512   // survivor capacity (per-wave 33rd-of-2048-sample threshold
                   // lands at global rank ~100-150; 128 was too small (round 7))

typedef float vf4 __attribute__((ext_vector_type(4)));

// ---------------------------------------------------------------------------
// Prep: pts4[j] = (x, y, z, sq), sq = (x*x + y*y) + z*z in exact reference
// rounding order (contract off, separate mul/add).
// ---------------------------------------------------------------------------
__global__ __launch_bounds__(256) void prep_kernel(const float* __restrict__ pts,
                                                   float4* __restrict__ pts4) {
#pragma clang fp contract(off)
    const int j = blockIdx.x * 256 + threadIdx.x;
    const float x = pts[j * 3 + 0];
    const float y = pts[j * 3 + 1];
    const float z = pts[j * 3 + 2];
    const float sq = (x * x + y * y) + z * z;
    pts4[j] = make_float4(x, y, z, sq);
}

// ---------------------------------------------------------------------------
// Select-only kernel (split from gather this round: the fused version's
// per-block critical path [select latency + gather] ~2x the per-point write
// budget with only ~3 blocks/CU resident; splitting lets select run at
// higher occupancy and gather run as a pure streaming kernel).
//
// Selection math byte-identical to rounds 6/9/12 (bit-identical output):
//   dist loop (d2-domain, 2-min tracking, sched_barrier every 8 iters to cap
//   in-flight loads / VGPR) -> per-wave ballot binary search (33rd of the
//   128-value {m1,m2} multiset, safe upper bound) -> min over waves ->
//   sqrt-closure widen -> compact survivors (CR sqrt only there) ->
//   all-pairs rank on (dist<<32|j) = lax.top_k order -> nbr[i*32+k].
// ---------------------------------------------------------------------------
__global__ __launch_bounds__(256) void knn_select_kernel(const float4* __restrict__ pts4,
                                                         int* __restrict__ nbr) {
#pragma clang fp contract(off)
    const int i = blockIdx.x;
    const int tid = threadIdx.x;
    const int lane = tid & 63;
    const int wv = tid >> 6;

    __shared__ unsigned red[4];
    __shared__ int sh_cnt;
    __shared__ unsigned long long S[SCAP];

    const float4 pi = pts4[i];

    unsigned d[32];                       // clamped-d2 bits per owned j
    unsigned m1 = 0xFFFFFFFFu, m2 = 0xFFFFFFFFu;
#pragma unroll
    for (int t = 0; t < 32; ++t) {
        const int j = tid + t * 256;
        const float4 pj = pts4[j];
        const float dot = __builtin_fmaf(pi.z, pj.z, __builtin_fmaf(pi.y, pj.y, pi.x * pj.x));
        const float d2 = (pi.w + pj.w) - (2.0f * dot);
        const unsigned db = __float_as_uint(fmaxf(d2, 0.0f));
        d[t] = db;
        const unsigned mx = db > m1 ? db : m1;   // max(db, m1)
        m1 = db < m1 ? db : m1;                  // min
        m2 = mx < m2 ? mx : m2;                  // 2nd smallest
        if ((t & 7) == 7) __builtin_amdgcn_sched_barrier(0);
    }
    if (tid == 0) sh_cnt = 0;

    // --- per-wave ballot binary search: exact 33rd smallest of {m1,m2} ---
    unsigned blo = 0u, bhi = 0x7F800000u;        // finite non-neg float bits
    while (blo < bhi) {
        const unsigned mid = (blo + bhi) >> 1;
        const int cnt = __popcll(__ballot(m1 <= mid)) + __popcll(__ballot(m2 <= mid));
        if (cnt >= KSEL) bhi = mid; else blo = mid + 1u;
    }
    if (lane == 0) red[wv] = bhi;
    __syncthreads();
    unsigned T = red[0];
    T = red[1] < T ? red[1] : T;
    T = red[2] < T ? red[2] : T;
    T = red[3] < T ? red[3] : T;

    // --- widen to sqrt-closure (conservative, provably inclusive) ---
    const float s = sqrtf(__uint_as_float(T));               // CR sqrt
    const float snx = __uint_as_float(__float_as_uint(s) + 1u);
    const unsigned T2 = __float_as_uint(__fmul_rn(snx, snx)) + 2u;

    // --- compact survivors into LDS (CR sqrt only here) ---
    int n = 0;
#pragma unroll
    for (int t = 0; t < 32; ++t) n += (d[t] <= T2) ? 1 : 0;

    int incl = n;
#pragma unroll
    for (int sh = 1; sh < 64; sh <<= 1) {
        const int o = __shfl_up(incl, sh, 64);
        if (lane >= sh) incl += o;
    }
    int base = 0;
    if (lane == 63) base = atomicAdd(&sh_cnt, incl);
    base = __shfl(base, 63, 64);
    int ptr = base + incl - n;
#pragma unroll
    for (int t = 0; t < 32; ++t) {
        if (d[t] <= T2) {
            const unsigned db = __float_as_uint(sqrtf(__uint_as_float(d[t])));
            if (ptr < SCAP)
                S[ptr] = (((unsigned long long)db) << 32) | (unsigned)(tid + t * 256);
            ++ptr;
        }
    }
    __syncthreads();

    // --- exact global rank among survivors -> nbr (keys unique via j) ---
    const int c = sh_cnt < SCAP ? sh_cnt : SCAP;
    for (int q = tid; q < c; q += 256) {
        const unsigned long long key = S[q];
        int rank = 0;
        for (int u = 0; u < c; ++u) rank += (S[u] < key) ? 1 : 0;
        if (rank >= 1 && rank < KSEL) nbr[i * 32 + (rank - 1)] = (int)(unsigned)key;
    }
}

// ---------------------------------------------------------------------------
// Gather-only kernel: pure streaming. One block per point. Read-once /
// store-many (out1/out2 rows are prefixes of out3's 32 rows): 33 row-reads,
// 57 row-stores per point. Wave wv owns k in {wv, wv+4, ..., wv+28}; 8
// up-front row loads (8 outstanding dwordx4), then NT float4 stores.
// Low VGPR -> high occupancy -> should approach the ~6.9 TB/s write behavior
// measured on fillBufferAligned.
// ---------------------------------------------------------------------------
__global__ __launch_bounds__(256) void gather_kernel(const float* __restrict__ feats,
                                                     const int* __restrict__ nbr,
                                                     float* __restrict__ out) {
    const int i = blockIdx.x;
    const int tid = threadIdx.x;
    const int lane = tid & 63;
    const int wv = tid >> 6;

    const unsigned long long O1 = (unsigned long long)NPTS * 256ull;
    const unsigned long long O2 = O1 + (unsigned long long)NPTS * 2048ull;
    const unsigned long long O3 = O2 + (unsigned long long)NPTS * 4096ull;
    const unsigned long long ii = (unsigned long long)i;

    // issue all row-reads first (8 neighbor rows per wave, + self on wave 0)
    vf4 vself;
    if (wv == 0) {
        const vf4* sp = (const vf4*)(feats + ii * 256ull);
        vself = sp[lane];
    }
    vf4 vk[8];
    unsigned kk[8];
#pragma unroll
    for (int m = 0; m < 8; ++m) {
        const int k = wv + 4 * m;
        const unsigned src = (unsigned)nbr[i * 32 + k];
        kk[m] = (unsigned)k;
        const vf4* sp = (const vf4*)(feats + (unsigned long long)src * 256ull);
        vk[m] = sp[lane];
    }

    // stores: out3 always; mirror to out2 (k<16) and out1 (k<8)
    if (wv == 0) {
        __builtin_nontemporal_store(vself, &((vf4*)(out + ii * 256ull))[lane]);
    }
#pragma unroll
    for (int m = 0; m < 8; ++m) {
        const unsigned k = kk[m];
        const vf4 v = vk[m];
        __builtin_nontemporal_store(v,
            &((vf4*)(out + O3 + ii * 8192ull + (unsigned long long)k * 256ull))[lane]);
        if (k < 16u)
            __builtin_nontemporal_store(v,
                &((vf4*)(out + O2 + ii * 4096ull + (unsigned long long)k * 256ull))[lane]);
        if (k < 8u)
            __builtin_nontemporal_store(v,
                &((vf4*)(out + O1 + ii * 2048ull + (unsigned long long)k * 256ull))[lane]);
    }
}

extern "C" void kernel_launch(void* const* d_in, const int* in_sizes, int n_in,
                              void* d_out, int out_size, void* d_ws, size_t ws_size,
                              hipStream_t stream) {
    const float* feats = (const float*)d_in[0];   // (8192, 256) f32
    const float* pts = (const float*)d_in[1];     // (8192, 3)   f32
    // d_in[2] = f_masks (all ones; unused by the reference computation)

    float4* pts4 = (float4*)d_ws;                         // 128 KB
    int* nbr = (int*)((char*)d_ws + NPTS * 16);           // 1 MB

    prep_kernel<<<NPTS / 256, 256, 0, stream>>>(pts, pts4);
    knn_select_kernel<<<NPTS, 256, 0, stream>>>(pts4, nbr);
    gather_kernel<<<NPTS, 256, 0, stream>>>(feats, nbr, (float*)d_out);
}

// Round 14
// 172.219 us; speedup vs baseline: 1.1480x; 1.1480x over previous
//
#include <hip/hip_runtime.h>

#define NPTS 8192
#define KSEL 33     // rank 0 (self) + 32 neighbors
#define TPB  512    // 8 waves/block: halves per-thread d[] (VGPR) vs 256/block
#define TSL  16     // candidate slots per thread (j = tid + t*512)
#define SCAP 1024   // survivor capacity. 8-wave sample = 1024 pts/wave ->
                    // wave-33rd bound ~ global rank 260; min-over-8 ~150-300
                    // survivors. 1024 = huge margin (round-7 lesson: audit
                    // capacity BEFORE benching).

typedef float vf4 __attribute__((ext_vector_type(4)));

// ---------------------------------------------------------------------------
// Prep: pts4[j] = (x, y, z, sq), sq = (x*x + y*y) + z*z in exact reference
// rounding order (contract off, separate mul/add).
// ---------------------------------------------------------------------------
__global__ __launch_bounds__(256) void prep_kernel(const float* __restrict__ pts,
                                                   float4* __restrict__ pts4) {
#pragma clang fp contract(off)
    const int j = blockIdx.x * 256 + threadIdx.x;
    const float x = pts[j * 3 + 0];
    const float y = pts[j * 3 + 1];
    const float z = pts[j * 3 + 2];
    const float sq = (x * x + y * y) + z * z;
    pts4[j] = make_float4(x, y, z, sq);
}

// ---------------------------------------------------------------------------
// Fused exact-kNN + gather, 512-thread (8-wave) blocks, one point per block.
// Fusion kept (round 13: split regressed — cross-block select/gather overlap
// is worth ~48 us). This round targets occupancy: d[16] instead of d[32],
// 4-in-flight loads (sched_barrier every 4) -> ~56-70 VGPR -> ~28-32
// waves/CU vs ~20.
//
// Selection math per-element identical to rounds 6..12 (exact reference d2
// bits; per-wave ballot binary search on the {m1,m2} 128-value multiset is
// a SAFE upper bound of the global 33rd d2 for any sample partition; CR-sqrt
// closure widen; all-pairs rank on (dist<<32|j) = lax.top_k order) ->
// bit-identical output.
// Gather: read-once / store-many; wave wv owns k in {wv, wv+8, wv+16, wv+24}
// -> 4 row reads, 7 NT row-stores per wave (+self on wave 0), balanced.
// ---------------------------------------------------------------------------
__global__ __launch_bounds__(TPB) void knn_fused_kernel(const float4* __restrict__ pts4,
                                                        const float* __restrict__ feats,
                                                        float* __restrict__ out) {
#pragma clang fp contract(off)
    const int i = blockIdx.x;
    const int tid = threadIdx.x;
    const int lane = tid & 63;
    const int wv = tid >> 6;

    __shared__ unsigned red[8];
    __shared__ int sh_cnt;
    __shared__ unsigned long long S[SCAP];
    __shared__ unsigned jlist[32];

    const float4 pi = pts4[i];
    const unsigned long long ii = (unsigned long long)i;

    // early self-row load (wave 0): independent of selection, huge latency slack
    vf4 vself;
    if (wv == 0) {
        const vf4* sp = (const vf4*)(feats + ii * 256ull);
        vself = sp[lane];
    }

    unsigned d[TSL];                      // clamped-d2 bits per owned j
    unsigned m1 = 0xFFFFFFFFu, m2 = 0xFFFFFFFFu;
#pragma unroll
    for (int t = 0; t < TSL; ++t) {
        const int j = tid + t * TPB;
        const float4 pj = pts4[j];
        const float dot = __builtin_fmaf(pi.z, pj.z, __builtin_fmaf(pi.y, pj.y, pi.x * pj.x));
        const float d2 = (pi.w + pj.w) - (2.0f * dot);
        const unsigned db = __float_as_uint(fmaxf(d2, 0.0f));
        d[t] = db;
        const unsigned mx = db > m1 ? db : m1;   // max(db, m1)
        m1 = db < m1 ? db : m1;                  // min
        m2 = mx < m2 ? mx : m2;                  // 2nd smallest
        if ((t & 3) == 3) __builtin_amdgcn_sched_barrier(0);  // cap in-flight loads
    }
    if (tid == 0) sh_cnt = 0;

    // --- per-wave ballot binary search: exact 33rd smallest of {m1,m2} ---
    unsigned blo = 0u, bhi = 0x7F800000u;        // finite non-neg float bits
    while (blo < bhi) {
        const unsigned mid = (blo + bhi) >> 1;
        const int cnt = __popcll(__ballot(m1 <= mid)) + __popcll(__ballot(m2 <= mid));
        if (cnt >= KSEL) bhi = mid; else blo = mid + 1u;
    }
    if (lane == 0) red[wv] = bhi;
    __syncthreads();
    unsigned T = red[0];
#pragma unroll
    for (int w = 1; w < 8; ++w) T = red[w] < T ? red[w] : T;

    // --- widen to sqrt-closure (conservative, provably inclusive) ---
    const float s = sqrtf(__uint_as_float(T));               // CR sqrt
    const float snx = __uint_as_float(__float_as_uint(s) + 1u);
    const unsigned T2 = __float_as_uint(__fmul_rn(snx, snx)) + 2u;

    // --- compact survivors into LDS (CR sqrt only here) ---
    int n = 0;
#pragma unroll
    for (int t = 0; t < TSL; ++t) n += (d[t] <= T2) ? 1 : 0;

    int incl = n;
#pragma unroll
    for (int sh = 1; sh < 64; sh <<= 1) {
        const int o = __shfl_up(incl, sh, 64);
        if (lane >= sh) incl += o;
    }
    int base = 0;
    if (lane == 63) base = atomicAdd(&sh_cnt, incl);
    base = __shfl(base, 63, 64);
    int ptr = base + incl - n;
#pragma unroll
    for (int t = 0; t < TSL; ++t) {
        if (d[t] <= T2) {
            const unsigned db = __float_as_uint(sqrtf(__uint_as_float(d[t])));
            if (ptr < SCAP)
                S[ptr] = (((unsigned long long)db) << 32) | (unsigned)(tid + t * TPB);
            ++ptr;
        }
    }
    __syncthreads();

    // --- exact global rank among survivors (keys unique via j) ---
    const int c = sh_cnt < SCAP ? sh_cnt : SCAP;
    for (int q = tid; q < c; q += TPB) {
        const unsigned long long key = S[q];
        int rank = 0;
        for (int u = 0; u < c; ++u) rank += (S[u] < key) ? 1 : 0;
        if (rank >= 1 && rank < KSEL) jlist[rank - 1] = (unsigned)key;
    }
    __syncthreads();

    // --- gather: read-once / store-many, 8 waves x 4 neighbor rows ---
    const unsigned long long O1 = (unsigned long long)NPTS * 256ull;
    const unsigned long long O2 = O1 + (unsigned long long)NPTS * 2048ull;
    const unsigned long long O3 = O2 + (unsigned long long)NPTS * 4096ull;

    vf4 vk[4];
#pragma unroll
    for (int m = 0; m < 4; ++m) {
        const unsigned src = jlist[wv + 8 * m];
        const vf4* sp = (const vf4*)(feats + (unsigned long long)src * 256ull);
        vk[m] = sp[lane];
    }

    if (wv == 0) {
        __builtin_nontemporal_store(vself, &((vf4*)(out + ii * 256ull))[lane]);
    }
#pragma unroll
    for (int m = 0; m < 4; ++m) {
        const unsigned k = (unsigned)(wv + 8 * m);
        const vf4 v = vk[m];
        __builtin_nontemporal_store(v,
            &((vf4*)(out + O3 + ii * 8192ull + (unsigned long long)k * 256ull))[lane]);
        if (k < 16u)
            __builtin_nontemporal_store(v,
                &((vf4*)(out + O2 + ii * 4096ull + (unsigned long long)k * 256ull))[lane]);
        if (k < 8u)
            __builtin_nontemporal_store(v,
                &((vf4*)(out + O1 + ii * 2048ull + (unsigned long long)k * 256ull))[lane]);
    }
}

extern "C" void kernel_launch(void* const* d_in, const int* in_sizes, int n_in,
                              void* d_out, int out_size, void* d_ws, size_t ws_size,
                              hipStream_t stream) {
    const float* feats = (const float*)d_in[0];   // (8192, 256) f32
    const float* pts = (const float*)d_in[1];     // (8192, 3)   f32
    // d_in[2] = f_masks (all ones; unused by the reference computation)

    float4* pts4 = (float4*)d_ws;                 // 128 KB scratch

    prep_kernel<<<NPTS / 256, 256, 0, stream>>>(pts, pts4);
    knn_fused_kernel<<<NPTS, TPB, 0, stream>>>(pts4, feats, (float*)d_out);
}

// Round 15
// 165.700 us; speedup vs baseline: 1.1932x; 1.0393x over previous
//
#include <hip/hip_runtime.h>

#define NPTS  8192
#define KSEL  33     // rank 0 (self) + 32 neighbors
#define SCAPW 256    // survivor capacity per wave. Wave-local threshold = 33rd
                     // of its own 2-min multiset over the FULL point set ->
                     // lands at global rank ~35-45 (E[lanes owning >=3 of
                     // top-33] ~ 1.3); survivors ~40-60. 256 = huge margin.

typedef float vf4 __attribute__((ext_vector_type(4)));

// Wave-internal LDS fence: ds_writes by other lanes of THIS wave visible to
// subsequent ds_reads (memory-carried dep the compiler can't track).
__device__ __forceinline__ void wave_lds_fence() {
    asm volatile("s_waitcnt lgkmcnt(0)" ::: "memory");
}

// ---------------------------------------------------------------------------
// Prep: pts4[j] = (x, y, z, sq), sq = (x*x + y*y) + z*z in exact reference
// rounding order (contract off, separate mul/add).
// ---------------------------------------------------------------------------
__global__ __launch_bounds__(256) void prep_kernel(const float* __restrict__ pts,
                                                   float4* __restrict__ pts4) {
#pragma clang fp contract(off)
    const int j = blockIdx.x * 256 + threadIdx.x;
    const float x = pts[j * 3 + 0];
    const float y = pts[j * 3 + 1];
    const float z = pts[j * 3 + 2];
    const float sq = (x * x + y * y) + z * z;
    pts4[j] = make_float4(x, y, z, sq);
}

// ---------------------------------------------------------------------------
// Wave-per-point fused kNN + gather. ZERO block barriers.
// Rounds 10-14 showed the 4-wave barrier-locked block phase-locks select
// (VALU) and gather (stores) across the whole CU; wave-per-point lets the
// CU's ~20-28 resident waves drift apart and mix the two pipes naturally.
//
// pass 1 (t=0..127, j=lane+t*64): exact reference d2 bits
//     dot = fma(z,z',fma(y,y',x*x')); d2c = max((sq_i+sq_j)-2*dot, 0)
//   track per-lane 2 smallest (m1<=m2).
// threshold: per-wave ballot binary search = 33rd smallest of the 128-value
//   {m1,m2} multiset — a SAFE upper bound on the global 33rd d2 (lanes
//   owning >=3 winners only raise it; partition-independent proof as rounds
//   6-14). Wave-local => no cross-wave reduce, no barrier.
// widen to CR-sqrt closure T2 (non-survivors strictly above the 33rd dist
//   even under tie-break) -> bit-identical selection.
// pass 2: recompute d2 (identical IEEE sequence => identical bits, proven
//   rounds 7/8), ballot-prefix compact survivors into this wave's LDS list,
//   CR sqrtf only for survivors; key = (dist<<32|j) = lax.top_k order.
// rank: all-pairs among c survivors -> jlist[0..31].
// gather: this wave copies self + 32 neighbor rows (1KB each, lane=vf4),
//   8-row batches, next batch's loads issued BEFORE this batch's NT stores
//   (in-order vmcnt decrement => load-waits never wait on stores).
// ---------------------------------------------------------------------------
__global__ __launch_bounds__(256) void knn_wave_kernel(const float4* __restrict__ pts4,
                                                       const float* __restrict__ feats,
                                                       float* __restrict__ out) {
#pragma clang fp contract(off)
    const int lane = threadIdx.x & 63;
    const int wv = threadIdx.x >> 6;
    const int i = blockIdx.x * 4 + wv;

    __shared__ unsigned long long Sall[4][SCAPW];
    __shared__ unsigned jl[4][32];
    unsigned long long* S = Sall[wv];
    unsigned* jlist = jl[wv];

    const float4 pi = pts4[i];
    const unsigned long long ii = (unsigned long long)i;

    // --- pass 1: 2-min tracking over this lane's 128 candidates ---
    unsigned m1 = 0xFFFFFFFFu, m2 = 0xFFFFFFFFu;
    for (int tt = 0; tt < 16; ++tt) {
#pragma unroll
        for (int u = 0; u < 8; ++u) {
            const int j = lane + (tt * 8 + u) * 64;
            const float4 pj = pts4[j];
            const float dot = __builtin_fmaf(pi.z, pj.z,
                               __builtin_fmaf(pi.y, pj.y, pi.x * pj.x));
            const float d2 = (pi.w + pj.w) - (2.0f * dot);
            const unsigned db = __float_as_uint(fmaxf(d2, 0.0f));
            const unsigned mx = db > m1 ? db : m1;
            m1 = db < m1 ? db : m1;
            m2 = mx < m2 ? mx : m2;
        }
        __builtin_amdgcn_sched_barrier(0);   // cap in-flight loads (VGPR)
    }

    // --- wave-local ballot binary search: 33rd smallest of {m1,m2} ---
    unsigned blo = 0u, bhi = 0x7F800000u;
    while (blo < bhi) {
        const unsigned mid = (blo + bhi) >> 1;
        const int cnt = __popcll(__ballot(m1 <= mid)) + __popcll(__ballot(m2 <= mid));
        if (cnt >= KSEL) bhi = mid; else blo = mid + 1u;
    }
    const unsigned T = bhi;

    // --- widen to sqrt-closure (conservative, provably inclusive) ---
    const float s = sqrtf(__uint_as_float(T));               // CR sqrt
    const float snx = __uint_as_float(__float_as_uint(s) + 1u);
    const unsigned T2 = __float_as_uint(__fmul_rn(snx, snx)) + 2u;

    // --- pass 2: recompute d2 (identical bits), ballot-prefix compact ---
    unsigned cnt = 0;
    for (int tt = 0; tt < 16; ++tt) {
#pragma unroll
        for (int u = 0; u < 8; ++u) {
            const int j = lane + (tt * 8 + u) * 64;
            const float4 pj = pts4[j];
            const float dot = __builtin_fmaf(pi.z, pj.z,
                               __builtin_fmaf(pi.y, pj.y, pi.x * pj.x));
            const float d2 = (pi.w + pj.w) - (2.0f * dot);
            const unsigned db = __float_as_uint(fmaxf(d2, 0.0f));
            const bool pred = (db <= T2);
            const unsigned long long bal = __ballot(pred);
            if (pred) {
                const unsigned sb = __float_as_uint(sqrtf(__uint_as_float(db)));
                const unsigned off = (unsigned)__popcll(bal & ((1ull << lane) - 1ull));
                if (cnt + off < SCAPW)
                    S[cnt + off] = (((unsigned long long)sb) << 32) | (unsigned)j;
            }
            cnt += (unsigned)__popcll(bal);
        }
        __builtin_amdgcn_sched_barrier(0);
    }
    wave_lds_fence();

    // --- exact global rank among survivors (keys unique via j) ---
    const int c = (int)(cnt < SCAPW ? cnt : SCAPW);
    for (int q = lane; q < c; q += 64) {
        const unsigned long long key = S[q];
        int rank = 0;
        for (int v = 0; v < c; ++v) rank += (S[v] < key) ? 1 : 0;
        if (rank >= 1 && rank < KSEL) jlist[rank - 1] = (unsigned)key;
    }
    wave_lds_fence();

    // --- gather: self + 32 rows, 8-row batches, loads-before-stores ---
    const unsigned long long O1 = (unsigned long long)NPTS * 256ull;
    const unsigned long long O2 = O1 + (unsigned long long)NPTS * 2048ull;
    const unsigned long long O3 = O2 + (unsigned long long)NPTS * 4096ull;

    // self row + first batch loads issued together
    const vf4 vself = ((const vf4*)(feats + ii * 256ull))[lane];
    vf4 cur[8];
#pragma unroll
    for (int m = 0; m < 8; ++m) {
        const unsigned src = jlist[m];
        cur[m] = ((const vf4*)(feats + (unsigned long long)src * 256ull))[lane];
    }
    __builtin_nontemporal_store(vself, &((vf4*)(out + ii * 256ull))[lane]);

    for (int b = 0; b < 4; ++b) {
        vf4 nxt[8];
        if (b < 3) {
#pragma unroll
            for (int m = 0; m < 8; ++m) {
                const unsigned src = jlist[(b + 1) * 8 + m];
                nxt[m] = ((const vf4*)(feats + (unsigned long long)src * 256ull))[lane];
            }
        }
#pragma unroll
        for (int m = 0; m < 8; ++m) {
            const unsigned k = (unsigned)(b * 8 + m);
            const vf4 v = cur[m];
            __builtin_nontemporal_store(v,
                &((vf4*)(out + O3 + ii * 8192ull + (unsigned long long)k * 256ull))[lane]);
            if (k < 16u)
                __builtin_nontemporal_store(v,
                    &((vf4*)(out + O2 + ii * 4096ull + (unsigned long long)k * 256ull))[lane]);
            if (k < 8u)
                __builtin_nontemporal_store(v,
                    &((vf4*)(out + O1 + ii * 2048ull + (unsigned long long)k * 256ull))[lane]);
        }
#pragma unroll
        for (int m = 0; m < 8; ++m) cur[m] = nxt[m];
    }
}

extern "C" void kernel_launch(void* const* d_in, const int* in_sizes, int n_in,
                              void* d_out, int out_size, void* d_ws, size_t ws_size,
                              hipStream_t stream) {
    const float* feats = (const float*)d_in[0];   // (8192, 256) f32
    const float* pts = (const float*)d_in[1];     // (8192, 3)   f32
    // d_in[2] = f_masks (all ones; unused by the reference computation)

    float4* pts4 = (float4*)d_ws;                 // 128 KB scratch

    prep_kernel<<<NPTS / 256, 256, 0, stream>>>(pts, pts4);
    knn_wave_kernel<<<NPTS / 4, 256, 0, stream>>>(pts4, feats, (float*)d_out);
}